// Round 4
// baseline (214.838 us; speedup 1.0000x reference)
//
#include <hip/hip_runtime.h>

// Problem constants (from reference setup_inputs)
#define BQ 4
#define CQ 3
#define HQ 512
#define WQ 512
#define VN 12000
#define FN 24000
#define UHN 1024
#define UWN 1024
#define IMGPLANE (HQ * WQ)

// workspace layout (byte offsets, all 16B-aligned)
#define MESHIMG_OFF 0u          // B*V*2 floats  = 384000 B
#define VALID_OFF   384000u     // FN*B bytes    =  96000 B
#define FD_OFF      480000u     // B*FN*8 floats = 3072000 B
#define IMGI_OFF    3552000u    // B*H*W*4 floats = 16777216 B
#define WS_NEED     (IMGI_OFF + (size_t)BQ * HQ * WQ * 4 * sizeof(float))

// ---------------------------------------------------------------------------
// Kernel 1 (fused): zero valid flags AND project mesh vertices.
// mesh_img[b][v][2]; valid_t is [FN][BQ] bytes.
// ---------------------------------------------------------------------------
__global__ void init_kernel(const float* __restrict__ mesh,
                            const float* __restrict__ focal,
                            const float* __restrict__ princpt,
                            const float* __restrict__ R,
                            const float* __restrict__ t,
                            float* __restrict__ mesh_img,
                            unsigned int* __restrict__ valid_u32) {
    int idx = blockIdx.x * blockDim.x + threadIdx.x;
    if (idx < (BQ * FN) / 4) valid_u32[idx] = 0u;   // 24000 words
    if (idx >= BQ * VN) return;                     // 48000 projections
    int b = idx / VN;
    const float* Rb = R + b * 9;
    const float* tb = t + b * 3;
    float mx = mesh[idx * 3 + 0];
    float my = mesh[idx * 3 + 1];
    float mz = mesh[idx * 3 + 2];
    float cx = Rb[0] * mx + Rb[1] * my + Rb[2] * mz + tb[0];
    float cy = Rb[3] * mx + Rb[4] * my + Rb[5] * mz + tb[1];
    float cz = Rb[6] * mx + Rb[7] * my + Rb[8] * mz + tb[2];
    float x = cx / cz * focal[b * 2 + 0] + princpt[b * 2 + 0];
    float y = cy / cz * focal[b * 2 + 1] + princpt[b * 2 + 1];
    mesh_img[idx * 2 + 0] = x;
    mesh_img[idx * 2 + 1] = y;
}

// ---------------------------------------------------------------------------
// Kernel 2 (fused prep): interleave img [b][c][y][x] -> img_i [b][y][x][4]
// AND scatter visibility flags from pix_to_face_xy (valid_t[f][b]).
// 4 pixels per thread.
// ---------------------------------------------------------------------------
__global__ void prep_kernel(const float* __restrict__ img,
                            float4* __restrict__ img_i,
                            const int4* __restrict__ ptf_xy4,
                            unsigned char* __restrict__ valid_t) {
    int i = blockIdx.x * blockDim.x + threadIdx.x;
    if (i >= (BQ * HQ * WQ) / 4) return;
    int g = i * 4;                         // first of 4 consecutive pixels
    int b = g >> 18;                       // HQ*WQ = 262144 = 2^18
    int p = g & (IMGPLANE - 1);

    // --- interleave ---
    const float* ib = img + (size_t)b * CQ * IMGPLANE + p;
    float4 r0 = *(const float4*)(ib);
    float4 r1 = *(const float4*)(ib + IMGPLANE);
    float4 r2 = *(const float4*)(ib + 2 * IMGPLANE);
    img_i[g + 0] = make_float4(r0.x, r1.x, r2.x, 0.0f);
    img_i[g + 1] = make_float4(r0.y, r1.y, r2.y, 0.0f);
    img_i[g + 2] = make_float4(r0.z, r1.z, r2.z, 0.0f);
    img_i[g + 3] = make_float4(r0.w, r1.w, r2.w, 0.0f);

    // --- visibility scatter (the -1 sentinel maps to face FN-1) ---
    int4 p4 = ptf_xy4[i];
    int pv[4] = {p4.x, p4.y, p4.z, p4.w};
#pragma unroll
    for (int k = 0; k < 4; ++k) {
        int l = (pv[k] != -1) ? (pv[k] - FN * b) : -1;
        if (l < 0) l += FN;
        valid_t[l * BQ + b] = 1;           // benign write race
    }
}

// ---------------------------------------------------------------------------
// Kernel 3: build per-(batch,face) gather record fd[b][f][8] =
//   {x0,y0, x1,y1, x2,y2, valid, 0}   (32B, one cache line touch)
// ---------------------------------------------------------------------------
__global__ void fd_kernel(const int* __restrict__ face,
                          const float* __restrict__ mesh_img,
                          const unsigned char* __restrict__ valid_t,
                          float4* __restrict__ fd) {
    int idx = blockIdx.x * blockDim.x + threadIdx.x;
    if (idx >= FN * BQ) return;
    int b = idx / FN;
    int f = idx - b * FN;
    int v0 = face[f * 3 + 0];
    int v1 = face[f * 3 + 1];
    int v2 = face[f * 3 + 2];
    const float* mi = mesh_img + (size_t)b * VN * 2;
    float4 a, c;
    a.x = mi[v0 * 2 + 0]; a.y = mi[v0 * 2 + 1];
    a.z = mi[v1 * 2 + 0]; a.w = mi[v1 * 2 + 1];
    c.x = mi[v2 * 2 + 0]; c.y = mi[v2 * 2 + 1];
    c.z = valid_t[f * BQ + b] ? 1.0f : 0.0f;
    c.w = 0.0f;
    fd[(size_t)idx * 2 + 0] = a;
    fd[(size_t)idx * 2 + 1] = c;
}

// ---------------------------------------------------------------------------
// Kernel 4: main fused pass.  ONE (pixel, batch) per thread, with an
// XCD-affinity swizzle: xcd = blk&7 -> batch = xcd>>1, so each XCD's L2
// only holds ONE batch's img_i (4MB) + fd slice (768KB).
// ---------------------------------------------------------------------------
__global__ void uv_kernel(const float4* __restrict__ img_i,
                          const float4* __restrict__ fd,
                          const int* __restrict__ ptf_uv,
                          const float* __restrict__ bary,
                          float* __restrict__ out) {
    int blk = blockIdx.x;                  // 16384 blocks exactly
    int r = blk & 7;
    int b = r >> 1;                        // batch pinned to XCD pair
    int pixBlk = ((blk >> 3) << 1) | (r & 1);
    int idx = pixBlk * 256 + threadIdx.x;  // uv pixel

    const size_t PLANE = (size_t)UHN * UWN;
    float* ob = out + (size_t)b * CQ * PLANE + idx;

    int puv = ptf_uv[idx];
    if (puv == -1) {
        __builtin_nontemporal_store(-1.0f, ob);
        __builtin_nontemporal_store(-1.0f, ob + PLANE);
        __builtin_nontemporal_store(-1.0f, ob + 2 * PLANE);
        return;
    }
    int pu = (puv < 0) ? puv + FN : puv;

    // 32B record: one line, all data for this (batch, face)
    const float4* fdp = fd + ((size_t)b * FN + pu) * 2;
    float4 fa = fdp[0];
    float4 fc = fdp[1];
    if (fc.z == 0.0f) {                    // invisible in this batch
        __builtin_nontemporal_store(-1.0f, ob);
        __builtin_nontemporal_store(-1.0f, ob + PLANE);
        __builtin_nontemporal_store(-1.0f, ob + 2 * PLANE);
        return;
    }

    float w0 = bary[idx * 3 + 0];
    float w1 = bary[idx * 3 + 1];
    float w2 = bary[idx * 3 + 2];

    float ux = w0 * fa.x + w1 * fa.z + w2 * fc.x;
    float uy = w0 * fa.y + w1 * fa.w + w2 * fc.y;

    // match reference's normalize -> denormalize round trip exactly
    float gx = ux / (float)(WQ - 1) * 2.0f - 1.0f;
    float gy = uy / (float)(HQ - 1) * 2.0f - 1.0f;
    float ix = (gx + 1.0f) * 0.5f * (float)(WQ - 1);
    float iy = (gy + 1.0f) * 0.5f * (float)(HQ - 1);

    float ix0 = floorf(ix), iy0 = floorf(iy);
    float wx1 = ix - ix0, wx0 = 1.0f - wx1;
    float wy1 = iy - iy0, wy0 = 1.0f - wy1;

    float xf[2] = {ix0, ix0 + 1.0f};
    float yf[2] = {iy0, iy0 + 1.0f};
    float wx[2] = {wx0, wx1};
    float wy[2] = {wy0, wy1};

    const float4* ibi = img_i + (size_t)b * IMGPLANE;
    float acc0 = 0.f, acc1 = 0.f, acc2 = 0.f;
#pragma unroll
    for (int ty = 0; ty < 2; ++ty) {
#pragma unroll
        for (int tx = 0; tx < 2; ++tx) {
            float wgt = wy[ty] * wx[tx];
            bool ok = (xf[tx] >= 0.0f) && (xf[tx] <= (float)(WQ - 1)) &&
                      (yf[ty] >= 0.0f) && (yf[ty] <= (float)(HQ - 1));
            float wv = ok ? wgt : 0.0f;
            int xi = (int)fminf(fmaxf(xf[tx], 0.0f), (float)(WQ - 1));
            int yi = (int)fminf(fmaxf(yf[ty], 0.0f), (float)(HQ - 1));
            float4 v = ibi[yi * WQ + xi];
            acc0 += v.x * wv;
            acc1 += v.y * wv;
            acc2 += v.z * wv;
        }
    }
    __builtin_nontemporal_store(acc0, ob);
    __builtin_nontemporal_store(acc1, ob + PLANE);
    __builtin_nontemporal_store(acc2, ob + 2 * PLANE);
}

// ---------------------------------------------------------------------------
// Fallback main pass (round-1 structure) used when ws_size is too small.
// ---------------------------------------------------------------------------
__global__ void uv_kernel_fb(const float* __restrict__ img,
                             const int* __restrict__ face,
                             const unsigned char* __restrict__ valid_t,
                             const float* __restrict__ mesh_img,
                             const int* __restrict__ ptf_uv,
                             const float* __restrict__ bary,
                             float* __restrict__ out) {
    int idx = blockIdx.x * blockDim.x + threadIdx.x;
    if (idx >= UHN * UWN) return;
    const size_t PLANE = (size_t)UHN * UWN;
    int puv = ptf_uv[idx];
    if (puv == -1) {
#pragma unroll
        for (int b = 0; b < BQ; ++b) {
            float* ob = out + (size_t)b * CQ * PLANE + idx;
            __builtin_nontemporal_store(-1.0f, ob);
            __builtin_nontemporal_store(-1.0f, ob + PLANE);
            __builtin_nontemporal_store(-1.0f, ob + 2 * PLANE);
        }
        return;
    }
    int pu = (puv < 0) ? puv + FN : puv;
    unsigned int vmask = *(const unsigned int*)(valid_t + (size_t)pu * BQ);
    float w0 = bary[idx * 3 + 0];
    float w1 = bary[idx * 3 + 1];
    float w2 = bary[idx * 3 + 2];
    int v0 = face[pu * 3 + 0];
    int v1 = face[pu * 3 + 1];
    int v2 = face[pu * 3 + 2];
#pragma unroll
    for (int b = 0; b < BQ; ++b) {
        float* ob = out + (size_t)b * CQ * PLANE + idx;
        bool vis = ((vmask >> (8 * b)) & 0xffu) != 0u;
        if (!vis) {
            __builtin_nontemporal_store(-1.0f, ob);
            __builtin_nontemporal_store(-1.0f, ob + PLANE);
            __builtin_nontemporal_store(-1.0f, ob + 2 * PLANE);
            continue;
        }
        const float* mi = mesh_img + (size_t)b * VN * 2;
        float ux = w0 * mi[v0 * 2 + 0] + w1 * mi[v1 * 2 + 0] + w2 * mi[v2 * 2 + 0];
        float uy = w0 * mi[v0 * 2 + 1] + w1 * mi[v1 * 2 + 1] + w2 * mi[v2 * 2 + 1];
        float gx = ux / (float)(WQ - 1) * 2.0f - 1.0f;
        float gy = uy / (float)(HQ - 1) * 2.0f - 1.0f;
        float ix = (gx + 1.0f) * 0.5f * (float)(WQ - 1);
        float iy = (gy + 1.0f) * 0.5f * (float)(HQ - 1);
        float ix0 = floorf(ix), iy0 = floorf(iy);
        float wx1 = ix - ix0, wx0 = 1.0f - wx1;
        float wy1 = iy - iy0, wy0 = 1.0f - wy1;
        float xf[2] = {ix0, ix0 + 1.0f};
        float yf[2] = {iy0, iy0 + 1.0f};
        float wx[2] = {wx0, wx1};
        float wy[2] = {wy0, wy1};
        float acc0 = 0.f, acc1 = 0.f, acc2 = 0.f;
        const float* ib = img + (size_t)b * CQ * IMGPLANE;
#pragma unroll
        for (int ty = 0; ty < 2; ++ty) {
#pragma unroll
            for (int tx = 0; tx < 2; ++tx) {
                float wgt = wy[ty] * wx[tx];
                bool ok = (xf[tx] >= 0.0f) && (xf[tx] <= (float)(WQ - 1)) &&
                          (yf[ty] >= 0.0f) && (yf[ty] <= (float)(HQ - 1));
                float wv = ok ? wgt : 0.0f;
                int xi = (int)fminf(fmaxf(xf[tx], 0.0f), (float)(WQ - 1));
                int yi = (int)fminf(fmaxf(yf[ty], 0.0f), (float)(HQ - 1));
                const float* ip = ib + yi * WQ + xi;
                acc0 += ip[0] * wv;
                acc1 += ip[IMGPLANE] * wv;
                acc2 += ip[2 * IMGPLANE] * wv;
            }
        }
        __builtin_nontemporal_store(acc0, ob);
        __builtin_nontemporal_store(acc1, ob + PLANE);
        __builtin_nontemporal_store(acc2, ob + 2 * PLANE);
    }
}

// ---------------------------------------------------------------------------
extern "C" void kernel_launch(void* const* d_in, const int* in_sizes, int n_in,
                              void* d_out, int out_size, void* d_ws, size_t ws_size,
                              hipStream_t stream) {
    const float* img     = (const float*)d_in[0];
    const float* mesh    = (const float*)d_in[1];
    const int*   face    = (const int*)d_in[2];
    const float* focal   = (const float*)d_in[3];
    const float* princpt = (const float*)d_in[4];
    const float* R       = (const float*)d_in[5];
    const float* t       = (const float*)d_in[6];
    const int*   ptf_xy  = (const int*)d_in[7];
    const int*   ptf_uv  = (const int*)d_in[8];
    const float* bary    = (const float*)d_in[9];
    float* out = (float*)d_out;

    unsigned char* ws = (unsigned char*)d_ws;
    float*         mesh_img = (float*)(ws + MESHIMG_OFF);
    unsigned char* valid_t  = ws + VALID_OFF;
    float4*        fd       = (float4*)(ws + FD_OFF);
    float4*        img_i    = (float4*)(ws + IMGI_OFF);

    init_kernel<<<(BQ * VN + 255) / 256, 256, 0, stream>>>(
        mesh, focal, princpt, R, t, mesh_img, (unsigned int*)valid_t);

    if (ws_size >= WS_NEED) {
        prep_kernel<<<((BQ * HQ * WQ / 4) + 255) / 256, 256, 0, stream>>>(
            img, img_i, (const int4*)ptf_xy, valid_t);

        fd_kernel<<<(FN * BQ + 255) / 256, 256, 0, stream>>>(
            face, mesh_img, valid_t, fd);

        // 4M (pixel,batch) threads; 16384 blocks of 256, XCD-swizzled
        uv_kernel<<<16384, 256, 0, stream>>>(img_i, fd, ptf_uv, bary, out);
    } else {
        // fallback: scatter-only valid pass + round-1 style main kernel
        prep_kernel<<<((BQ * HQ * WQ / 4) + 255) / 256, 256, 0, stream>>>(
            img, img_i, (const int4*)ptf_xy, valid_t);  // requires img_i space
        uv_kernel_fb<<<(UHN * UWN + 255) / 256, 256, 0, stream>>>(
            img, face, valid_t, mesh_img, ptf_uv, bary, out);
    }
}

// Round 12
// 188.520 us; speedup vs baseline: 1.1396x; 1.1396x over previous
//
#include <hip/hip_runtime.h>

// Problem constants (from reference setup_inputs)
#define BQ 4
#define CQ 3
#define HQ 512
#define WQ 512
#define VN 12000
#define FN 24000
#define UHN 1024
#define UWN 1024
#define IMGPLANE (HQ * WQ)
#define VWORDS 768   // ceil(FN/32)=750, padded

// native vector type for nontemporal float4 stores
typedef float fx4 __attribute__((ext_vector_type(4)));

// workspace layout (byte offsets, all 16B-aligned)
#define MESHIMG_OFF 0u          // B*V*2 floats   = 384000 B
#define VBITS_OFF   384000u     // B*VWORDS u32   =  12288 B
#define FD_OFF      396288u     // B*FN*8 floats  = 3072000 B
#define IMGI_OFF    3468288u    // B*H*W*4 floats = 16777216 B

// ---------------------------------------------------------------------------
// Kernel 1 (fused): zero visibility bitmask AND project mesh vertices.
// mesh_img[b][v][2]
// ---------------------------------------------------------------------------
__global__ void init_kernel(const float* __restrict__ mesh,
                            const float* __restrict__ focal,
                            const float* __restrict__ princpt,
                            const float* __restrict__ R,
                            const float* __restrict__ t,
                            float* __restrict__ mesh_img,
                            unsigned int* __restrict__ vbits) {
    int idx = blockIdx.x * blockDim.x + threadIdx.x;
    if (idx < BQ * VWORDS) vbits[idx] = 0u;         // 3072 words
    if (idx >= BQ * VN) return;                     // 48000 projections
    int b = idx / VN;
    const float* Rb = R + b * 9;
    const float* tb = t + b * 3;
    float mx = mesh[idx * 3 + 0];
    float my = mesh[idx * 3 + 1];
    float mz = mesh[idx * 3 + 2];
    float cx = Rb[0] * mx + Rb[1] * my + Rb[2] * mz + tb[0];
    float cy = Rb[3] * mx + Rb[4] * my + Rb[5] * mz + tb[1];
    float cz = Rb[6] * mx + Rb[7] * my + Rb[8] * mz + tb[2];
    float x = cx / cz * focal[b * 2 + 0] + princpt[b * 2 + 0];
    float y = cy / cz * focal[b * 2 + 1] + princpt[b * 2 + 1];
    mesh_img[idx * 2 + 0] = x;
    mesh_img[idx * 2 + 1] = y;
}

// ---------------------------------------------------------------------------
// Kernel 2: interleave img [b][c][y][x] -> img_i [b][y][x][4]  (4 px/thread)
// ---------------------------------------------------------------------------
__global__ void interleave_kernel(const float* __restrict__ img,
                                  float4* __restrict__ img_i) {
    int i = blockIdx.x * blockDim.x + threadIdx.x;
    if (i >= (BQ * HQ * WQ) / 4) return;
    int g = i * 4;
    int b = g >> 18;                       // HQ*WQ = 262144 = 2^18
    int p = g & (IMGPLANE - 1);
    const float* ib = img + (size_t)b * CQ * IMGPLANE + p;
    float4 r0 = *(const float4*)(ib);
    float4 r1 = *(const float4*)(ib + IMGPLANE);
    float4 r2 = *(const float4*)(ib + 2 * IMGPLANE);
    img_i[g + 0] = make_float4(r0.x, r1.x, r2.x, 0.0f);
    img_i[g + 1] = make_float4(r0.y, r1.y, r2.y, 0.0f);
    img_i[g + 2] = make_float4(r0.z, r1.z, r2.z, 0.0f);
    img_i[g + 3] = make_float4(r0.w, r1.w, r2.w, 0.0f);
}

// ---------------------------------------------------------------------------
// Kernel 3: visibility scatter via per-block LDS bitmask.
// 256 blocks: 64 blocks per batch, 4096 pixels per block (16 px/thread).
// Replaces 4M divergent global byte-stores with LDS atomics + ~192K word ORs.
// The -1 sentinel maps to face FN-1, exactly like the reference.
// ---------------------------------------------------------------------------
__global__ __launch_bounds__(256) void valid_kernel(const int4* __restrict__ ptf_xy4,
                                                    unsigned int* __restrict__ vbits) {
    __shared__ unsigned int lb[VWORDS];
    int tid = threadIdx.x;
    for (int i = tid; i < VWORDS; i += 256) lb[i] = 0u;
    __syncthreads();
    int b = blockIdx.x >> 6;               // 64 blocks per batch
    int blkInB = blockIdx.x & 63;
    const int4* src = ptf_xy4 + ((size_t)b * IMGPLANE + blkInB * 4096) / 4;
#pragma unroll
    for (int k = 0; k < 4; ++k) {
        int4 p4 = src[tid + k * 256];
        int pv[4] = {p4.x, p4.y, p4.z, p4.w};
#pragma unroll
        for (int j = 0; j < 4; ++j) {
            int l = (pv[j] != -1) ? (pv[j] - FN * b) : -1;
            if (l < 0) l += FN;
            atomicOr(&lb[l >> 5], 1u << (l & 31));
        }
    }
    __syncthreads();
    for (int i = tid; i < VWORDS; i += 256) {
        unsigned int w = lb[i];
        if (w) atomicOr(&vbits[b * VWORDS + i], w);
    }
}

// ---------------------------------------------------------------------------
// Kernel 4: build per-(batch,face) gather record fd[b][f][8] =
//   {x0,y0, x1,y1, x2,y2, valid, 0}   (32B, one cache-line touch)
// ---------------------------------------------------------------------------
__global__ void fd_kernel(const int* __restrict__ face,
                          const float* __restrict__ mesh_img,
                          const unsigned int* __restrict__ vbits,
                          float4* __restrict__ fd) {
    int idx = blockIdx.x * blockDim.x + threadIdx.x;
    if (idx >= FN * BQ) return;
    int b = idx / FN;
    int f = idx - b * FN;
    int v0 = face[f * 3 + 0];
    int v1 = face[f * 3 + 1];
    int v2 = face[f * 3 + 2];
    const float* mi = mesh_img + (size_t)b * VN * 2;
    float4 a, c;
    a.x = mi[v0 * 2 + 0]; a.y = mi[v0 * 2 + 1];
    a.z = mi[v1 * 2 + 0]; a.w = mi[v1 * 2 + 1];
    c.x = mi[v2 * 2 + 0]; c.y = mi[v2 * 2 + 1];
    c.z = (float)((vbits[b * VWORDS + (f >> 5)] >> (f & 31)) & 1u);
    c.w = 0.0f;
    fd[(size_t)idx * 2 + 0] = a;
    fd[(size_t)idx * 2 + 1] = c;
}

// ---------------------------------------------------------------------------
// Kernel 5: main fused pass.  4 consecutive pixels x 1 batch per thread,
// XCD-affinity swizzle (batch pinned to XCD pair), branchless, phase-
// structured so all 8 fd loads then all 16 tap loads are in flight together.
// 4096 blocks x 256 threads.
// ---------------------------------------------------------------------------
__global__ __launch_bounds__(256) void uv_kernel(const float4* __restrict__ img_i,
                                                 const float4* __restrict__ fd,
                                                 const int* __restrict__ ptf_uv,
                                                 const float* __restrict__ bary,
                                                 float* __restrict__ out) {
    int blk = blockIdx.x;                  // 4096 blocks exactly
    int r = blk & 7;
    int b = r >> 1;                        // batch pinned to XCD pair
    int pixBlk = ((blk >> 3) << 1) | (r & 1);   // [0,1024)
    int p0 = pixBlk * 1024 + (threadIdx.x << 2);   // 4 consecutive uv pixels

    const size_t PLANE = (size_t)UHN * UWN;

    // streaming loads (fully coalesced)
    int4 puv4 = *(const int4*)(ptf_uv + p0);
    float4 by0 = *(const float4*)(bary + (size_t)p0 * 3);
    float4 by1 = *(const float4*)(bary + (size_t)p0 * 3 + 4);
    float4 by2 = *(const float4*)(bary + (size_t)p0 * 3 + 8);

    int pin[4] = {puv4.x, puv4.y, puv4.z, puv4.w};
    float bw[12] = {by0.x, by0.y, by0.z, by0.w,
                    by1.x, by1.y, by1.z, by1.w,
                    by2.x, by2.y, by2.z, by2.w};

    // phase 1: all fd records (8 independent divergent loads)
    const float4* fdb = fd + (size_t)b * FN * 2;
    float4 fa[4], fc[4];
    int pu[4];
#pragma unroll
    for (int k = 0; k < 4; ++k) {
        int p = pin[k];
        pu[k] = (p < 0) ? p + FN : p;
        fa[k] = fdb[pu[k] * 2 + 0];
        fc[k] = fdb[pu[k] * 2 + 1];
    }

    // phase 2: compute tap addresses/weights, issue all 16 tap loads
    const float4* ibi = img_i + (size_t)b * IMGPLANE;
    float4 t00[4], t01[4], t10[4], t11[4];
    float g00[4], g01[4], g10[4], g11[4];
#pragma unroll
    for (int k = 0; k < 4; ++k) {
        float w0 = bw[3 * k + 0], w1 = bw[3 * k + 1], w2 = bw[3 * k + 2];
        float ux = w0 * fa[k].x + w1 * fa[k].z + w2 * fc[k].x;
        float uy = w0 * fa[k].y + w1 * fa[k].w + w2 * fc[k].y;

        // match reference's normalize -> denormalize round trip exactly
        float gx = ux / (float)(WQ - 1) * 2.0f - 1.0f;
        float gy = uy / (float)(HQ - 1) * 2.0f - 1.0f;
        float ix = (gx + 1.0f) * 0.5f * (float)(WQ - 1);
        float iy = (gy + 1.0f) * 0.5f * (float)(HQ - 1);

        float ix0 = floorf(ix), iy0 = floorf(iy);
        float wx1 = ix - ix0, wx0 = 1.0f - wx1;
        float wy1 = iy - iy0, wy0 = 1.0f - wy1;
        float ix1 = ix0 + 1.0f, iy1 = iy0 + 1.0f;

        bool x0ok = (ix0 >= 0.0f) && (ix0 <= (float)(WQ - 1));
        bool x1ok = (ix1 >= 0.0f) && (ix1 <= (float)(WQ - 1));
        bool y0ok = (iy0 >= 0.0f) && (iy0 <= (float)(HQ - 1));
        bool y1ok = (iy1 >= 0.0f) && (iy1 <= (float)(HQ - 1));

        g00[k] = (y0ok && x0ok) ? wy0 * wx0 : 0.0f;
        g01[k] = (y0ok && x1ok) ? wy0 * wx1 : 0.0f;
        g10[k] = (y1ok && x0ok) ? wy1 * wx0 : 0.0f;
        g11[k] = (y1ok && x1ok) ? wy1 * wx1 : 0.0f;

        int xi0 = (int)fminf(fmaxf(ix0, 0.0f), (float)(WQ - 1));
        int xi1 = (int)fminf(fmaxf(ix1, 0.0f), (float)(WQ - 1));
        int yi0 = (int)fminf(fmaxf(iy0, 0.0f), (float)(HQ - 1));
        int yi1 = (int)fminf(fmaxf(iy1, 0.0f), (float)(HQ - 1));

        t00[k] = ibi[yi0 * WQ + xi0];
        t01[k] = ibi[yi0 * WQ + xi1];
        t10[k] = ibi[yi1 * WQ + xi0];
        t11[k] = ibi[yi1 * WQ + xi1];
    }

    // phase 3: combine (same tap order/accumulation text as before) + select
    float o0[4], o1[4], o2[4];
#pragma unroll
    for (int k = 0; k < 4; ++k) {
        float acc0 = 0.f, acc1 = 0.f, acc2 = 0.f;
        acc0 += t00[k].x * g00[k]; acc1 += t00[k].y * g00[k]; acc2 += t00[k].z * g00[k];
        acc0 += t01[k].x * g01[k]; acc1 += t01[k].y * g01[k]; acc2 += t01[k].z * g01[k];
        acc0 += t10[k].x * g10[k]; acc1 += t10[k].y * g10[k]; acc2 += t10[k].z * g10[k];
        acc0 += t11[k].x * g11[k]; acc1 += t11[k].y * g11[k]; acc2 += t11[k].z * g11[k];
        bool ok = (pin[k] != -1) && (fc[k].z != 0.0f);
        o0[k] = ok ? acc0 : -1.0f;
        o1[k] = ok ? acc1 : -1.0f;
        o2[k] = ok ? acc2 : -1.0f;
    }

    // coalesced nontemporal float4 stores via native vector type
    float* ob = out + (size_t)b * CQ * PLANE + p0;
    fx4 s0 = {o0[0], o0[1], o0[2], o0[3]};
    fx4 s1 = {o1[0], o1[1], o1[2], o1[3]};
    fx4 s2 = {o2[0], o2[1], o2[2], o2[3]};
    __builtin_nontemporal_store(s0, (fx4*)(ob));
    __builtin_nontemporal_store(s1, (fx4*)(ob + PLANE));
    __builtin_nontemporal_store(s2, (fx4*)(ob + 2 * PLANE));
}

// ---------------------------------------------------------------------------
extern "C" void kernel_launch(void* const* d_in, const int* in_sizes, int n_in,
                              void* d_out, int out_size, void* d_ws, size_t ws_size,
                              hipStream_t stream) {
    const float* img     = (const float*)d_in[0];
    const float* mesh    = (const float*)d_in[1];
    const int*   face    = (const int*)d_in[2];
    const float* focal   = (const float*)d_in[3];
    const float* princpt = (const float*)d_in[4];
    const float* R       = (const float*)d_in[5];
    const float* t       = (const float*)d_in[6];
    const int*   ptf_xy  = (const int*)d_in[7];
    const int*   ptf_uv  = (const int*)d_in[8];
    const float* bary    = (const float*)d_in[9];
    float* out = (float*)d_out;

    unsigned char* ws = (unsigned char*)d_ws;
    float*         mesh_img = (float*)(ws + MESHIMG_OFF);
    unsigned int*  vbits    = (unsigned int*)(ws + VBITS_OFF);
    float4*        fd       = (float4*)(ws + FD_OFF);
    float4*        img_i    = (float4*)(ws + IMGI_OFF);

    init_kernel<<<(BQ * VN + 255) / 256, 256, 0, stream>>>(
        mesh, focal, princpt, R, t, mesh_img, vbits);

    interleave_kernel<<<(BQ * HQ * WQ / 4) / 256, 256, 0, stream>>>(img, img_i);

    valid_kernel<<<256, 256, 0, stream>>>((const int4*)ptf_xy, vbits);

    fd_kernel<<<(FN * BQ + 255) / 256, 256, 0, stream>>>(
        face, mesh_img, vbits, fd);

    // 4M (pixel,batch) work items; 4096 blocks x 256 threads x 4 px
    uv_kernel<<<4096, 256, 0, stream>>>(img_i, fd, ptf_uv, bary, out);
}